// Round 9
// baseline (130.348 us; speedup 1.0000x reference)
//
#include <hip/hip_runtime.h>
#include <hip/hip_bf16.h>

// 15x15 VALID conv as banded-Toeplitz MFMA (bf16 in, fp32 accum).
// Per ky: O_tile[16x16] += A(16x32 image patch) x B_ky(32x16 Toeplitz),
// B_ky[k][n] = w[ky][k-n] for 0<=k-n<=14 else 0. 15 MFMAs per output tile.
//
// R9 (from rocprof R8: VGPR_Count=44 proves compiler demoted bf[15] to
// per-iteration LDS rebuilds -> register-starved pipeline, all pipes <40%):
//  - asm-pin bf[ky] after one-time build (forces 60-VGPR hold, no remat).
//  - __launch_bounds__(256,3): VGPR cap 168 -> room for bf + acc + ~6
//    in-flight A-frags (deep lgkmcnt pipelining). 3 blocks/CU x 4 waves.
//  - keep R8: BN=80, 192B slab stride (bank-uniform), XCD swizzle, bias fold.

#define IN_DIM   4096
#define OUT_DIM  4082
#define KDIM     15
#define BM       128
#define BN       80
#define NTX      5             // 16-col output tiles per block
#define SLAB_R   142           // BM + 14
#define SLAB_CE  96            // bf16 elems per slab row
#define SLAB_CB  192           // bytes per slab row
#define SLAB_CH  12            // 16-B chunks per row
#define GRID_X   52            // ceil(4082/80)
#define GRID_Y   32            // ceil(4082/128)
#define NWG      (GRID_X * GRID_Y)   // 1664 = 8 * 208
#define CPX      (NWG / 8)           // 208 blocks per XCD

typedef __attribute__((ext_vector_type(8))) short  short8;
typedef __attribute__((ext_vector_type(4))) float  f32x4;

__global__ __launch_bounds__(256, 3) void conv15_mfma(
    const float* __restrict__ X, const float* __restrict__ Wt,
    const float* __restrict__ bias, float* __restrict__ out) {
  __shared__ __align__(16) unsigned short sX[SLAB_R * SLAB_CE];  // 27648 B
  __shared__ __align__(16) unsigned short sW[KDIM * KDIM];       // 450 B

  const int tid = threadIdx.x;

  // ---- XCD-aware bijective swizzle (1664 = 8 XCDs x 208) ----
  const int bid = blockIdx.x;
  const int lin = (bid & 7) * CPX + (bid >> 3);
  const int bx  = lin % GRID_X;
  const int by  = lin / GRID_X;
  const int x0 = bx * BN;
  const int y0 = by * BM;

  // ---- compact bf16 weight table ----
  if (tid < KDIM * KDIM) {
    __hip_bfloat16 h = __float2bfloat16(Wt[tid]);
    sW[tid] = *reinterpret_cast<const unsigned short*>(&h);
  }

  // ---- stage input slab (f32 -> bf16), linear writes (byte = 16*idx) ----
  for (int idx = tid; idx < SLAB_R * SLAB_CH; idx += 256) {
    const int r = idx / SLAB_CH;
    const int c = idx - r * SLAB_CH;
    int gr = y0 + r;           if (gr > IN_DIM - 1) gr = IN_DIM - 1;
    int gc = x0 + c * 8;       if (gc > IN_DIM - 8) gc = IN_DIM - 8;
    // clamped rows/cols only ever feed band-zero or unstored outputs
    const float* p = X + (size_t)gr * IN_DIM + gc;
    const f32x4 a = *reinterpret_cast<const f32x4*>(p);
    const f32x4 b = *reinterpret_cast<const f32x4*>(p + 4);
    float f[8] = {a.x, a.y, a.z, a.w, b.x, b.y, b.z, b.w};
    short8 pk;
#pragma unroll
    for (int j = 0; j < 8; ++j) {
      __hip_bfloat16 h = __float2bfloat16(f[j]);
      pk[j] = *reinterpret_cast<const short*>(&h);
    }
    *reinterpret_cast<short8*>(
        reinterpret_cast<char*>(sX) + r * SLAB_CB + c * 16) = pk;
  }
  __syncthreads();

  const int lane = tid & 63;
  const int wv   = tid >> 6;
  const int m    = lane & 15;   // A row within tile / D col
  const int g    = lane >> 4;   // k-chunk / D row-quad

  // ---- build B fragments ONCE, pin into registers ----
  short8 bf[KDIM];
#pragma unroll
  for (int ky = 0; ky < KDIM; ++ky) {
    short8 t;
#pragma unroll
    for (int j = 0; j < 8; ++j) {
      const int kx = g * 8 + j - m;
      const int cl = kx < 0 ? 0 : (kx > 14 ? 14 : kx);
      const unsigned short v = sW[ky * KDIM + cl];
      t[j] = (kx >= 0 && kx <= 14) ? (short)v : (short)0;
    }
    bf[ky] = t;
    asm volatile("" : "+v"(bf[ky]));   // force materialization; forbid remat
  }

  // ---- accumulators (bias folded into init) ----
  const float bv = bias[0];
  f32x4 acc[2][NTX];
#pragma unroll
  for (int a = 0; a < 2; ++a)
#pragma unroll
    for (int b = 0; b < NTX; ++b)
      acc[a][b] = (f32x4){bv, bv, bv, bv};

  // base addr per ty; all reads use compile-time immediates
  const char* base0 = reinterpret_cast<const char*>(sX)
                    + (32 * wv + m) * SLAB_CB + 16 * g;
  const char* base1 = base0 + 16 * SLAB_CB;

#pragma unroll
  for (int ky = 0; ky < KDIM; ++ky) {
#pragma unroll
    for (int xt = 0; xt < NTX; ++xt) {
      const short8 a0 = *reinterpret_cast<const short8*>(
          base0 + ky * SLAB_CB + 32 * xt);
      acc[0][xt] = __builtin_amdgcn_mfma_f32_16x16x32_bf16(
          a0, bf[ky], acc[0][xt], 0, 0, 0);
    }
#pragma unroll
    for (int xt = 0; xt < NTX; ++xt) {
      const short8 a1 = *reinterpret_cast<const short8*>(
          base1 + ky * SLAB_CB + 32 * xt);
      acc[1][xt] = __builtin_amdgcn_mfma_f32_16x16x32_bf16(
          a1, bf[ky], acc[1][xt], 0, 0, 0);
    }
  }

  // ---- store: D col = lane&15, row = (lane>>4)*4 + reg  [m89/m91] ----
#pragma unroll
  for (int ty = 0; ty < 2; ++ty) {
    const int gy0 = y0 + (2 * wv + ty) * 16 + g * 4;
#pragma unroll
    for (int xt = 0; xt < NTX; ++xt) {
      const int ox = x0 + xt * 16 + m;
      if (ox < OUT_DIM) {
#pragma unroll
        for (int q = 0; q < 4; ++q) {
          const int oy = gy0 + q;
          if (oy < OUT_DIM)
            out[(size_t)oy * OUT_DIM + ox] = acc[ty][xt][q];
        }
      }
    }
  }
}

extern "C" void kernel_launch(void* const* d_in, const int* in_sizes, int n_in,
                              void* d_out, int out_size, void* d_ws, size_t ws_size,
                              hipStream_t stream) {
  const float* X    = (const float*)d_in[0];
  const float* Wt   = (const float*)d_in[1];
  const float* bias = (const float*)d_in[2];
  float* out = (float*)d_out;

  conv15_mfma<<<NWG, 256, 0, stream>>>(X, Wt, bias, out);
}